// Round 4
// baseline (369.533 us; speedup 1.0000x reference)
//
#include <hip/hip_runtime.h>
#include <hip/hip_bf16.h>

#define HW 262144            // 512*512
#define IW 512
#define TW 64
#define TH 8
#define HLW 66               // TW+2
#define NHALO 660            // 66*10
#define ROWU 40              // ushorts per halo-px row (80 B): 64B data + 4B bscale + pad

typedef __attribute__((ext_vector_type(8))) short short8;
typedef __attribute__((ext_vector_type(4))) float f32x4;
typedef __attribute__((ext_vector_type(4))) unsigned int uint4v;

static __device__ inline unsigned int bpack2(float a, float b) {
  __hip_bfloat16 ha = __float2bfloat16(a);
  __hip_bfloat16 hb = __float2bfloat16(b);
  unsigned short ua = *reinterpret_cast<unsigned short*>(&ha);
  unsigned short ub = *reinterpret_cast<unsigned short*>(&hb);
  return (unsigned int)ua | ((unsigned int)ub << 16);
}

// ---------------- Kernel 1: GAP of relu(conv1x1(y)) -> per-block partials ----
__global__ __launch_bounds__(256) void k_gap(
    const float* __restrict__ y, const float* __restrict__ fuse_w,
    const float* __restrict__ fuse_b, float* __restrict__ partial) {
  __shared__ float fw[80], fb[16];
  __shared__ float red[4][16];
  int tid = threadIdx.x;
  if (tid < 80) fw[tid] = fuse_w[tid];
  if (tid < 16) fb[tid] = fuse_b[tid];
  __syncthreads();

  int b = blockIdx.x >> 7;           // 8 batches
  int chunk = blockIdx.x & 127;      // 128 chunks of 2048 px
  const float* yb = y + (size_t)b * 5 * HW + chunk * 2048;

  float sums[16];
#pragma unroll
  for (int o = 0; o < 16; ++o) sums[o] = 0.f;

  for (int i = 0; i < 2048; i += 256) {
    int p = i + tid;
    float yv[5];
#pragma unroll
    for (int c = 0; c < 5; ++c) yv[c] = yb[c * HW + p];
#pragma unroll
    for (int o = 0; o < 16; ++o) {
      float a = fb[o];
#pragma unroll
      for (int c = 0; c < 5; ++c) a = fmaf(fw[o * 5 + c], yv[c], a);
      sums[o] += fmaxf(a, 0.f);
    }
  }

  int lane = tid & 63, wv = tid >> 6;
#pragma unroll
  for (int o = 0; o < 16; ++o) {
    float v = sums[o];
    for (int off = 32; off > 0; off >>= 1) v += __shfl_down(v, off);
    if (lane == 0) red[wv][o] = v;
  }
  __syncthreads();
  if (tid < 16)
    partial[blockIdx.x * 16 + tid] =
        red[0][tid] + red[1][tid] + red[2][tid] + red[3][tid];
}

// ---------------- Kernel 2: SE MLP + fold se into boundary weights ----------
__global__ __launch_bounds__(256) void k_se(
    const float* __restrict__ partial, const float* __restrict__ se_w1,
    const float* __restrict__ se_w2, const float* __restrict__ bd_w,
    float* __restrict__ bd_eff) {
  int tid = threadIdx.x;
  int b = tid >> 5, sub = tid & 31;
  float g[16];
#pragma unroll
  for (int c = 0; c < 16; ++c) g[c] = 0.f;
#pragma unroll
  for (int k = 0; k < 4; ++k) {
    const float* p = partial + (b * 128 + sub + k * 32) * 16;
#pragma unroll
    for (int c = 0; c < 16; ++c) g[c] += p[c];
  }
#pragma unroll
  for (int c = 0; c < 16; ++c) {
    float v = g[c];
    v += __shfl_xor(v, 1);  v += __shfl_xor(v, 2);
    v += __shfl_xor(v, 4);  v += __shfl_xor(v, 8);
    v += __shfl_xor(v, 16);
    g[c] = v * (1.f / 262144.f);
  }
  if (sub == 0) {
    float h[16];
#pragma unroll
    for (int j = 0; j < 16; ++j) {
      float s = 0.f;
#pragma unroll
      for (int c = 0; c < 16; ++c) s += g[c] * se_w1[j * 16 + c];
      h[j] = fmaxf(s, 0.f);
    }
#pragma unroll
    for (int i = 0; i < 5; ++i) {
      float s = 0.f;
#pragma unroll
      for (int j = 0; j < 16; ++j) s += h[j] * se_w2[i * 16 + j];
      float se = 1.f / (1.f + expf(-s));
      bd_eff[b * 10 + i]     = bd_w[i] * se;
      bd_eff[b * 10 + 5 + i] = bd_w[5 + i] * se;
    }
  }
}

// ---------------- Kernel 2b: repack fc_w -> wTab[s][oc][ci] bf16 ------------
__global__ void k_prep(const float* __restrict__ fc_w,
                       unsigned short* __restrict__ wTab) {
  int i = blockIdx.x * 256 + threadIdx.x;   // (s*16+oc)*32+ci, 4608 total
  if (i < 4608) {
    int ci = i & 31, rest = i >> 5;
    int oc = rest & 15, s = rest >> 4;
    float v = fc_w[(oc * 32 + ci) * 9 + s];
    __hip_bfloat16 h = __float2bfloat16(v);
    wTab[i] = *reinterpret_cast<unsigned short*>(&h);
  }
}

// ---------------- Kernel 3: fused main (MFMA implicit-GEMM conv) ------------
// 512 threads = 8 waves; wave wv owns output row wv of the 64x8 tile.
__global__ __launch_bounds__(512, 4) void k_main(
    const float* __restrict__ x, const float* __restrict__ y,
    const float* __restrict__ fuse_w, const float* __restrict__ fuse_b,
    const unsigned short* __restrict__ wTab,
    const float* __restrict__ bd_eff, const float* __restrict__ bd_b,
    const float* __restrict__ fc_b,
    const float* __restrict__ fm_w, const float* __restrict__ fm_b,
    const float* __restrict__ cv_w, const float* __restrict__ cv_b,
    float* __restrict__ out) {
  __shared__ unsigned short tile[NHALO * ROWU];   // 52800 B
  __shared__ float scbuf[512];
  __shared__ float s_fw[80], s_fb[16], s_bde[10], s_bdb[2], s_fm[32],
      s_fmb[2], s_cv[16], s_cvb[16], s_fcb[16];

  int tid = threadIdx.x;
  int bsel = blockIdx.z;
  int h0 = blockIdx.y * TH;
  int w0 = blockIdx.x * TW;

  if (tid < 80) s_fw[tid] = fuse_w[tid];
  else if (tid < 96)  s_fb[tid - 80]   = fuse_b[tid - 80];
  else if (tid < 106) s_bde[tid - 96]  = bd_eff[bsel * 10 + tid - 96];
  else if (tid < 108) s_bdb[tid - 106] = bd_b[tid - 106];
  else if (tid < 140) s_fm[tid - 108]  = fm_w[tid - 108];
  else if (tid < 142) s_fmb[tid - 140] = fm_b[tid - 140];
  else if (tid < 158) s_cv[tid - 142]  = cv_w[tid - 142];
  else if (tid < 174) s_cvb[tid - 158] = cv_b[tid - 158];
  else if (tid < 190) s_fcb[tid - 174] = fc_b[tid - 174];

  int lane = tid & 63, wv = tid >> 6;   // wv 0..7
  int l15 = lane & 15, q = lane >> 4;

  // A-fragments: lane l -> oc=l15, ci = q*8+j, for each of 9 (kh,kw) steps
  short8 afrag[9];
#pragma unroll
  for (int s = 0; s < 9; ++s)
    afrag[s] = *reinterpret_cast<const short8*>(wTab + (s * 16 + l15) * 32 + q * 8);

  __syncthreads();   // scalar tables ready

  // ---- stage halo tile: ch0-15 = x bf16, ch16-31 = fuse bf16, +bscale f32 --
  const float* yb = y + (size_t)bsel * 5 * HW;
  const float* xb = x + (size_t)bsel * 16 * HW;
  for (int p = tid; p < NHALO; p += 512) {
    int hr = p / HLW, wc = p - hr * HLW;
    int gh = h0 - 1 + hr, gw = w0 - 1 + wc;
    bool valid = (gh >= 0) & (gh < IW) & (gw >= 0) & (gw < IW);
    uint4v blk0 = {0, 0, 0, 0}, blk1 = {0, 0, 0, 0},
           blk2 = {0, 0, 0, 0}, blk3 = {0, 0, 0, 0};
    float bsc = 0.f;
    if (valid) {
      int gofs = gh * IW + gw;
      float xv[16], yv[5];
#pragma unroll
      for (int c = 0; c < 16; ++c) xv[c] = xb[c * HW + gofs];
#pragma unroll
      for (int c = 0; c < 5; ++c) yv[c] = yb[c * HW + gofs];
      float fo[16];
#pragma unroll
      for (int o = 0; o < 16; ++o) {
        float a = s_fb[o];
#pragma unroll
        for (int c = 0; c < 5; ++c) a = fmaf(s_fw[o * 5 + c], yv[c], a);
        fo[o] = fmaxf(a, 0.f);
      }
      // boundary head (se folded), softmax fg prob
      float bl0 = s_bdb[0], bl1 = s_bdb[1];
#pragma unroll
      for (int c = 0; c < 5; ++c) {
        bl0 = fmaf(s_bde[c], yv[c], bl0);
        bl1 = fmaf(s_bde[5 + c], yv[c], bl1);
      }
      bsc = 1.f / (1.f + __expf(bl0 - bl1));
      blk0 = uint4v{bpack2(xv[0], xv[1]), bpack2(xv[2], xv[3]),
                    bpack2(xv[4], xv[5]), bpack2(xv[6], xv[7])};
      blk1 = uint4v{bpack2(xv[8], xv[9]), bpack2(xv[10], xv[11]),
                    bpack2(xv[12], xv[13]), bpack2(xv[14], xv[15])};
      blk2 = uint4v{bpack2(fo[0], fo[1]), bpack2(fo[2], fo[3]),
                    bpack2(fo[4], fo[5]), bpack2(fo[6], fo[7])};
      blk3 = uint4v{bpack2(fo[8], fo[9]), bpack2(fo[10], fo[11]),
                    bpack2(fo[12], fo[13]), bpack2(fo[14], fo[15])};
    }
    uint4v* dst = reinterpret_cast<uint4v*>(&tile[p * ROWU]);
    dst[0] = blk0; dst[1] = blk1; dst[2] = blk2; dst[3] = blk3;
    *reinterpret_cast<float*>(&tile[p * ROWU + 32]) = bsc;   // byte offset 64
  }
  __syncthreads();

  // ---- 4 pixel-groups per wave: 9 MFMA + mask head -> sc ----
  const char* tbase = reinterpret_cast<const char*>(tile);
  int row = wv;
  float scv[4];
#pragma unroll
  for (int g = 0; g < 4; ++g) {
    int c0 = g * 16;
    int hp0 = row * HLW + c0 + l15;
    const char* bp = tbase + hp0 * (ROWU * 2) + q * 16;

    f32x4 acc = {0.f, 0.f, 0.f, 0.f};
#pragma unroll
    for (int kh = 0; kh < 3; ++kh) {
#pragma unroll
      for (int kw = 0; kw < 3; ++kw) {
        short8 bfr = *reinterpret_cast<const short8*>(
            bp + (kh * HLW + kw) * (ROWU * 2));
        acc = __builtin_amdgcn_mfma_f32_16x16x32_bf16(afrag[kh * 3 + kw], bfr,
                                                      acc, 0, 0, 0);
      }
    }

    float pm0 = 0.f, pm1 = 0.f;
#pragma unroll
    for (int j = 0; j < 4; ++j) {
      int oc = q * 4 + j;
      float fv = fmaxf(acc[j] + s_fcb[oc], 0.f);
      pm0 = fmaf(s_fm[oc], fv, pm0);
      pm1 = fmaf(s_fm[16 + oc], fv, pm1);
    }
    pm0 += __shfl_xor(pm0, 16); pm0 += __shfl_xor(pm0, 32);
    pm1 += __shfl_xor(pm1, 16); pm1 += __shfl_xor(pm1, 32);
    float mscale = 1.f / (1.f + __expf((pm0 + s_fmb[0]) - (pm1 + s_fmb[1])));
    float bsc = *reinterpret_cast<const float*>(
        tbase + ((row + 1) * HLW + c0 + l15 + 1) * (ROWU * 2) + 64);
    scv[g] = fminf(fmaxf(mscale + bsc, 0.f), 1.f);
  }

  if (q == 0) {
#pragma unroll
    for (int g = 0; g < 4; ++g) scbuf[wv * 64 + g * 16 + l15] = scv[g];
  }
  __syncthreads();

  // ---- vectorized store phase: 2048 float4 stores, fully coalesced ----
  float* outb = out + (size_t)bsel * 16 * HW;
#pragma unroll
  for (int it = 0; it < 4; ++it) {
    int t = tid + it * 512;
    int oc = t >> 7, grp = t & 127;
    int p = grp * 4, prow = p >> 6, pcol = p & 63;
    f32x4 sv = *reinterpret_cast<const f32x4*>(&scbuf[p]);
    float cw = s_cv[oc], cb = s_cvb[oc];
    f32x4 ov = {fmaf(cw, sv[0], cb), fmaf(cw, sv[1], cb),
                fmaf(cw, sv[2], cb), fmaf(cw, sv[3], cb)};
    *reinterpret_cast<f32x4*>(
        &outb[(size_t)oc * HW + (h0 + prow) * IW + w0 + pcol]) = ov;
  }
}

extern "C" void kernel_launch(void* const* d_in, const int* in_sizes, int n_in,
                              void* d_out, int out_size, void* d_ws, size_t ws_size,
                              hipStream_t stream) {
  const float* x      = (const float*)d_in[0];
  const float* y      = (const float*)d_in[1];
  const float* fuse_w = (const float*)d_in[2];
  const float* fuse_b = (const float*)d_in[3];
  const float* se_w1  = (const float*)d_in[4];
  const float* se_w2  = (const float*)d_in[5];
  const float* bd_w   = (const float*)d_in[6];
  const float* bd_b   = (const float*)d_in[7];
  const float* fc_w   = (const float*)d_in[8];
  const float* fc_b   = (const float*)d_in[9];
  const float* fm_w   = (const float*)d_in[10];
  const float* fm_b   = (const float*)d_in[11];
  const float* cv_w   = (const float*)d_in[12];
  const float* cv_b   = (const float*)d_in[13];
  float* out = (float*)d_out;

  float* partial = (float*)d_ws;                              // 16384 floats
  float* bd_eff  = partial + 1024 * 16;                       // 80 floats
  unsigned short* wTab =
      (unsigned short*)((char*)d_ws + (1024 * 16 + 80) * 4);  // 4608 ushort

  k_gap<<<1024, 256, 0, stream>>>(y, fuse_w, fuse_b, partial);
  k_se<<<1, 256, 0, stream>>>(partial, se_w1, se_w2, bd_w, bd_eff);
  k_prep<<<18, 256, 0, stream>>>(fc_w, wTab);
  k_main<<<dim3(8, 64, 8), 512, 0, stream>>>(x, y, fuse_w, fuse_b, wTab,
                                             bd_eff, bd_b, fc_b, fm_w, fm_b,
                                             cv_w, cv_b, out);
}

// Round 5
// 199.501 us; speedup vs baseline: 1.8523x; 1.8523x over previous
//
#include <hip/hip_runtime.h>
#include <hip/hip_bf16.h>

#define HW 262144            // 512*512
#define IW 512
#define TW 64
#define TH 8
#define HLW 66               // TW+2
#define NHALO 660            // 66*10
#define ROWU 40              // ushorts per halo-px row (80 B): 64B data + 4B bscale + pad

typedef __attribute__((ext_vector_type(8))) short short8;
typedef __attribute__((ext_vector_type(4))) float f32x4;
typedef __attribute__((ext_vector_type(4))) unsigned int uint4v;

static __device__ inline unsigned int bpack2(float a, float b) {
  __hip_bfloat16 ha = __float2bfloat16(a);
  __hip_bfloat16 hb = __float2bfloat16(b);
  unsigned short ua = *reinterpret_cast<unsigned short*>(&ha);
  unsigned short ub = *reinterpret_cast<unsigned short*>(&hb);
  return (unsigned int)ua | ((unsigned int)ub << 16);
}

// ---------------- Kernel 1: GAP of relu(conv1x1(y)) -> per-block partials ----
__global__ __launch_bounds__(256) void k_gap(
    const float* __restrict__ y, const float* __restrict__ fuse_w,
    const float* __restrict__ fuse_b, float* __restrict__ partial) {
  __shared__ float fw[80], fb[16];
  __shared__ float red[4][16];
  int tid = threadIdx.x;
  if (tid < 80) fw[tid] = fuse_w[tid];
  if (tid < 16) fb[tid] = fuse_b[tid];
  __syncthreads();

  int b = blockIdx.x >> 7;           // 8 batches
  int chunk = blockIdx.x & 127;      // 128 chunks of 2048 px
  const float* yb = y + (size_t)b * 5 * HW + chunk * 2048;

  float sums[16];
#pragma unroll
  for (int o = 0; o < 16; ++o) sums[o] = 0.f;

  for (int i = 0; i < 2048; i += 256) {
    int p = i + tid;
    float yv[5];
#pragma unroll
    for (int c = 0; c < 5; ++c) yv[c] = yb[c * HW + p];
#pragma unroll
    for (int o = 0; o < 16; ++o) {
      float a = fb[o];
#pragma unroll
      for (int c = 0; c < 5; ++c) a = fmaf(fw[o * 5 + c], yv[c], a);
      sums[o] += fmaxf(a, 0.f);
    }
  }

  int lane = tid & 63, wv = tid >> 6;
#pragma unroll
  for (int o = 0; o < 16; ++o) {
    float v = sums[o];
    for (int off = 32; off > 0; off >>= 1) v += __shfl_down(v, off);
    if (lane == 0) red[wv][o] = v;
  }
  __syncthreads();
  if (tid < 16)
    partial[blockIdx.x * 16 + tid] =
        red[0][tid] + red[1][tid] + red[2][tid] + red[3][tid];
}

// ---------------- Kernel 2: SE MLP + fold se into boundary weights ----------
__global__ __launch_bounds__(256) void k_se(
    const float* __restrict__ partial, const float* __restrict__ se_w1,
    const float* __restrict__ se_w2, const float* __restrict__ bd_w,
    float* __restrict__ bd_eff) {
  int tid = threadIdx.x;
  int b = tid >> 5, sub = tid & 31;
  float g[16];
#pragma unroll
  for (int c = 0; c < 16; ++c) g[c] = 0.f;
#pragma unroll
  for (int k = 0; k < 4; ++k) {
    const float* p = partial + (b * 128 + sub + k * 32) * 16;
#pragma unroll
    for (int c = 0; c < 16; ++c) g[c] += p[c];
  }
#pragma unroll
  for (int c = 0; c < 16; ++c) {
    float v = g[c];
    v += __shfl_xor(v, 1);  v += __shfl_xor(v, 2);
    v += __shfl_xor(v, 4);  v += __shfl_xor(v, 8);
    v += __shfl_xor(v, 16);
    g[c] = v * (1.f / 262144.f);
  }
  if (sub == 0) {
    float h[16];
#pragma unroll
    for (int j = 0; j < 16; ++j) {
      float s = 0.f;
#pragma unroll
      for (int c = 0; c < 16; ++c) s += g[c] * se_w1[j * 16 + c];
      h[j] = fmaxf(s, 0.f);
    }
#pragma unroll
    for (int i = 0; i < 5; ++i) {
      float s = 0.f;
#pragma unroll
      for (int j = 0; j < 16; ++j) s += h[j] * se_w2[i * 16 + j];
      float se = 1.f / (1.f + expf(-s));
      bd_eff[b * 10 + i]     = bd_w[i] * se;
      bd_eff[b * 10 + 5 + i] = bd_w[5 + i] * se;
    }
  }
}

// ---------------- Kernel 2b: repack fc_w -> wTab[s][oc][ci] bf16 ------------
__global__ void k_prep(const float* __restrict__ fc_w,
                       unsigned short* __restrict__ wTab) {
  int i = blockIdx.x * 256 + threadIdx.x;   // (s*16+oc)*32+ci, 4608 total
  if (i < 4608) {
    int ci = i & 31, rest = i >> 5;
    int oc = rest & 15, s = rest >> 4;
    float v = fc_w[(oc * 32 + ci) * 9 + s];
    __hip_bfloat16 h = __float2bfloat16(v);
    wTab[i] = *reinterpret_cast<unsigned short*>(&h);
  }
}

// ---------------- Kernel 3: fused main (MFMA implicit-GEMM conv) ------------
// 512 threads = 8 waves; wave wv owns output row wv of the 64x8 tile.
// launch_bounds min-waves kept LOW: LDS (53KB) already caps at 2 blocks/CU;
// demanding more forced VGPR=64 + scratch spills last round (FETCH 512MB,
// WRITE 727MB, 3x slowdown).
__global__ __launch_bounds__(512, 2) void k_main(
    const float* __restrict__ x, const float* __restrict__ y,
    const float* __restrict__ fuse_w, const float* __restrict__ fuse_b,
    const unsigned short* __restrict__ wTab,
    const float* __restrict__ bd_eff, const float* __restrict__ bd_b,
    const float* __restrict__ fc_b,
    const float* __restrict__ fm_w, const float* __restrict__ fm_b,
    const float* __restrict__ cv_w, const float* __restrict__ cv_b,
    float* __restrict__ out) {
  __shared__ unsigned short tile[NHALO * ROWU];   // 52800 B
  __shared__ float scbuf[512];
  __shared__ float s_fw[80], s_fb[16], s_bde[10], s_bdb[2], s_fm[32],
      s_fmb[2], s_cv[16], s_cvb[16], s_fcb[16];

  int tid = threadIdx.x;
  int bsel = blockIdx.z;
  int h0 = blockIdx.y * TH;
  int w0 = blockIdx.x * TW;

  if (tid < 80) s_fw[tid] = fuse_w[tid];
  else if (tid < 96)  s_fb[tid - 80]   = fuse_b[tid - 80];
  else if (tid < 106) s_bde[tid - 96]  = bd_eff[bsel * 10 + tid - 96];
  else if (tid < 108) s_bdb[tid - 106] = bd_b[tid - 106];
  else if (tid < 140) s_fm[tid - 108]  = fm_w[tid - 108];
  else if (tid < 142) s_fmb[tid - 140] = fm_b[tid - 140];
  else if (tid < 158) s_cv[tid - 142]  = cv_w[tid - 142];
  else if (tid < 174) s_cvb[tid - 158] = cv_b[tid - 158];
  else if (tid < 190) s_fcb[tid - 174] = fc_b[tid - 174];

  int lane = tid & 63, wv = tid >> 6;   // wv 0..7
  int l15 = lane & 15, q = lane >> 4;

  // A-fragments: lane l -> oc=l15, ci = q*8+j, for each of 9 (kh,kw) steps
  short8 afrag[9];
#pragma unroll
  for (int s = 0; s < 9; ++s)
    afrag[s] = *reinterpret_cast<const short8*>(wTab + (s * 16 + l15) * 32 + q * 8);

  __syncthreads();   // scalar tables ready

  // ---- stage halo tile: ch0-15 = x bf16, ch16-31 = fuse bf16, +bscale f32 --
  // Chunked (8ch at a time) to keep register live-ranges small -> no spills.
  const float* yb = y + (size_t)bsel * 5 * HW;
  const float* xb = x + (size_t)bsel * 16 * HW;
  for (int p = tid; p < NHALO; p += 512) {
    int hr = p / HLW, wc = p - hr * HLW;
    int gh = h0 - 1 + hr, gw = w0 - 1 + wc;
    bool valid = (gh >= 0) & (gh < IW) & (gw >= 0) & (gw < IW);
    uint4v* dst = reinterpret_cast<uint4v*>(&tile[p * ROWU]);
    if (valid) {
      int gofs = gh * IW + gw;
      {
        float a0 = xb[gofs],          a1 = xb[HW + gofs];
        float a2 = xb[2 * HW + gofs], a3 = xb[3 * HW + gofs];
        float a4 = xb[4 * HW + gofs], a5 = xb[5 * HW + gofs];
        float a6 = xb[6 * HW + gofs], a7 = xb[7 * HW + gofs];
        dst[0] = uint4v{bpack2(a0, a1), bpack2(a2, a3),
                        bpack2(a4, a5), bpack2(a6, a7)};
      }
      {
        float a0 = xb[8 * HW + gofs],  a1 = xb[9 * HW + gofs];
        float a2 = xb[10 * HW + gofs], a3 = xb[11 * HW + gofs];
        float a4 = xb[12 * HW + gofs], a5 = xb[13 * HW + gofs];
        float a6 = xb[14 * HW + gofs], a7 = xb[15 * HW + gofs];
        dst[1] = uint4v{bpack2(a0, a1), bpack2(a2, a3),
                        bpack2(a4, a5), bpack2(a6, a7)};
      }
      {
        float yv[5];
#pragma unroll
        for (int c = 0; c < 5; ++c) yv[c] = yb[c * HW + gofs];
        float fo[8];
#pragma unroll
        for (int o = 0; o < 8; ++o) {
          float a = s_fb[o];
#pragma unroll
          for (int c = 0; c < 5; ++c) a = fmaf(s_fw[o * 5 + c], yv[c], a);
          fo[o] = fmaxf(a, 0.f);
        }
        dst[2] = uint4v{bpack2(fo[0], fo[1]), bpack2(fo[2], fo[3]),
                        bpack2(fo[4], fo[5]), bpack2(fo[6], fo[7])};
#pragma unroll
        for (int o = 0; o < 8; ++o) {
          float a = s_fb[8 + o];
#pragma unroll
          for (int c = 0; c < 5; ++c) a = fmaf(s_fw[(8 + o) * 5 + c], yv[c], a);
          fo[o] = fmaxf(a, 0.f);
        }
        dst[3] = uint4v{bpack2(fo[0], fo[1]), bpack2(fo[2], fo[3]),
                        bpack2(fo[4], fo[5]), bpack2(fo[6], fo[7])};
        // boundary head (se folded), softmax fg prob
        float bl0 = s_bdb[0], bl1 = s_bdb[1];
#pragma unroll
        for (int c = 0; c < 5; ++c) {
          bl0 = fmaf(s_bde[c], yv[c], bl0);
          bl1 = fmaf(s_bde[5 + c], yv[c], bl1);
        }
        *reinterpret_cast<float*>(&tile[p * ROWU + 32]) =
            1.f / (1.f + __expf(bl0 - bl1));
      }
    } else {
      uint4v z = {0, 0, 0, 0};
      dst[0] = z; dst[1] = z; dst[2] = z; dst[3] = z;
      *reinterpret_cast<float*>(&tile[p * ROWU + 32]) = 0.f;
    }
  }
  __syncthreads();

  // ---- 4 pixel-groups per wave: 9 MFMA + mask head -> sc ----
  const char* tbase = reinterpret_cast<const char*>(tile);
  int row = wv;
  float scv[4];
#pragma unroll
  for (int g = 0; g < 4; ++g) {
    int c0 = g * 16;
    int hp0 = row * HLW + c0 + l15;
    const char* bp = tbase + hp0 * (ROWU * 2) + q * 16;

    f32x4 acc = {0.f, 0.f, 0.f, 0.f};
#pragma unroll
    for (int kh = 0; kh < 3; ++kh) {
#pragma unroll
      for (int kw = 0; kw < 3; ++kw) {
        short8 bfr = *reinterpret_cast<const short8*>(
            bp + (kh * HLW + kw) * (ROWU * 2));
        acc = __builtin_amdgcn_mfma_f32_16x16x32_bf16(afrag[kh * 3 + kw], bfr,
                                                      acc, 0, 0, 0);
      }
    }

    float pm0 = 0.f, pm1 = 0.f;
#pragma unroll
    for (int j = 0; j < 4; ++j) {
      int oc = q * 4 + j;
      float fv = fmaxf(acc[j] + s_fcb[oc], 0.f);
      pm0 = fmaf(s_fm[oc], fv, pm0);
      pm1 = fmaf(s_fm[16 + oc], fv, pm1);
    }
    pm0 += __shfl_xor(pm0, 16); pm0 += __shfl_xor(pm0, 32);
    pm1 += __shfl_xor(pm1, 16); pm1 += __shfl_xor(pm1, 32);
    float mscale = 1.f / (1.f + __expf((pm0 + s_fmb[0]) - (pm1 + s_fmb[1])));
    float bsc = *reinterpret_cast<const float*>(
        tbase + ((row + 1) * HLW + c0 + l15 + 1) * (ROWU * 2) + 64);
    scv[g] = fminf(fmaxf(mscale + bsc, 0.f), 1.f);
  }

  if (q == 0) {
#pragma unroll
    for (int g = 0; g < 4; ++g) scbuf[wv * 64 + g * 16 + l15] = scv[g];
  }
  __syncthreads();

  // ---- vectorized store phase: 2048 float4 stores, fully coalesced ----
  float* outb = out + (size_t)bsel * 16 * HW;
#pragma unroll
  for (int it = 0; it < 4; ++it) {
    int t = tid + it * 512;
    int oc = t >> 7, grp = t & 127;
    int p = grp * 4, prow = p >> 6, pcol = p & 63;
    f32x4 sv = *reinterpret_cast<const f32x4*>(&scbuf[p]);
    float cw = s_cv[oc], cb = s_cvb[oc];
    f32x4 ov = {fmaf(cw, sv[0], cb), fmaf(cw, sv[1], cb),
                fmaf(cw, sv[2], cb), fmaf(cw, sv[3], cb)};
    *reinterpret_cast<f32x4*>(
        &outb[(size_t)oc * HW + (h0 + prow) * IW + w0 + pcol]) = ov;
  }
}

extern "C" void kernel_launch(void* const* d_in, const int* in_sizes, int n_in,
                              void* d_out, int out_size, void* d_ws, size_t ws_size,
                              hipStream_t stream) {
  const float* x      = (const float*)d_in[0];
  const float* y      = (const float*)d_in[1];
  const float* fuse_w = (const float*)d_in[2];
  const float* fuse_b = (const float*)d_in[3];
  const float* se_w1  = (const float*)d_in[4];
  const float* se_w2  = (const float*)d_in[5];
  const float* bd_w   = (const float*)d_in[6];
  const float* bd_b   = (const float*)d_in[7];
  const float* fc_w   = (const float*)d_in[8];
  const float* fc_b   = (const float*)d_in[9];
  const float* fm_w   = (const float*)d_in[10];
  const float* fm_b   = (const float*)d_in[11];
  const float* cv_w   = (const float*)d_in[12];
  const float* cv_b   = (const float*)d_in[13];
  float* out = (float*)d_out;

  float* partial = (float*)d_ws;                              // 16384 floats
  float* bd_eff  = partial + 1024 * 16;                       // 80 floats
  unsigned short* wTab =
      (unsigned short*)((char*)d_ws + (1024 * 16 + 80) * 4);  // 4608 ushort

  k_gap<<<1024, 256, 0, stream>>>(y, fuse_w, fuse_b, partial);
  k_se<<<1, 256, 0, stream>>>(partial, se_w1, se_w2, bd_w, bd_eff);
  k_prep<<<18, 256, 0, stream>>>(fc_w, wTab);
  k_main<<<dim3(8, 64, 8), 512, 0, stream>>>(x, y, fuse_w, fuse_b, wTab,
                                             bd_eff, bd_b, fc_b, fm_w, fm_b,
                                             cv_w, cv_b, out);
}

// Round 6
// 144.758 us; speedup vs baseline: 2.5528x; 1.3782x over previous
//
#include <hip/hip_runtime.h>
#include <hip/hip_bf16.h>

#define HW 262144            // 512*512
#define IW 512
#define TW 64
#define TH 8
#define HLW 66               // TW+2
#define NHALO 660            // 66*10
#define ROWU 40              // ushorts/halo px: 32B x | 32B fuse | 4B bscale | 12B pad

typedef __attribute__((ext_vector_type(8))) short short8;
typedef __attribute__((ext_vector_type(4))) float f32x4;
typedef __attribute__((ext_vector_type(4))) unsigned int uint4v;

static __device__ inline unsigned int bpack2(float a, float b) {
  __hip_bfloat16 ha = __float2bfloat16(a);
  __hip_bfloat16 hb = __float2bfloat16(b);
  unsigned short ua = *reinterpret_cast<unsigned short*>(&ha);
  unsigned short ub = *reinterpret_cast<unsigned short*>(&hb);
  return (unsigned int)ua | ((unsigned int)ub << 16);
}

// ---------------- Kernel 1: GAP of relu(conv1x1(y)) -> per-block partials ----
__global__ __launch_bounds__(256) void k_gap(
    const float* __restrict__ y, const float* __restrict__ fuse_w,
    const float* __restrict__ fuse_b, float* __restrict__ partial) {
  __shared__ float fw[80], fb[16];
  __shared__ float red[4][16];
  int tid = threadIdx.x;
  if (tid < 80) fw[tid] = fuse_w[tid];
  if (tid < 16) fb[tid] = fuse_b[tid];
  __syncthreads();

  int b = blockIdx.x >> 7;
  int chunk = blockIdx.x & 127;
  const float* yb = y + (size_t)b * 5 * HW + chunk * 2048;

  float sums[16];
#pragma unroll
  for (int o = 0; o < 16; ++o) sums[o] = 0.f;

  for (int i = 0; i < 2048; i += 256) {
    int p = i + tid;
    float yv[5];
#pragma unroll
    for (int c = 0; c < 5; ++c) yv[c] = yb[c * HW + p];
#pragma unroll
    for (int o = 0; o < 16; ++o) {
      float a = fb[o];
#pragma unroll
      for (int c = 0; c < 5; ++c) a = fmaf(fw[o * 5 + c], yv[c], a);
      sums[o] += fmaxf(a, 0.f);
    }
  }

  int lane = tid & 63, wv = tid >> 6;
#pragma unroll
  for (int o = 0; o < 16; ++o) {
    float v = sums[o];
    for (int off = 32; off > 0; off >>= 1) v += __shfl_down(v, off);
    if (lane == 0) red[wv][o] = v;
  }
  __syncthreads();
  if (tid < 16)
    partial[blockIdx.x * 16 + tid] =
        red[0][tid] + red[1][tid] + red[2][tid] + red[3][tid];
}

// ---------------- Kernel 2: SE MLP + fold se into boundary weights ----------
__global__ __launch_bounds__(256) void k_se(
    const float* __restrict__ partial, const float* __restrict__ se_w1,
    const float* __restrict__ se_w2, const float* __restrict__ bd_w,
    float* __restrict__ bd_eff) {
  int tid = threadIdx.x;
  int b = tid >> 5, sub = tid & 31;
  float g[16];
#pragma unroll
  for (int c = 0; c < 16; ++c) g[c] = 0.f;
#pragma unroll
  for (int k = 0; k < 4; ++k) {
    const float* p = partial + (b * 128 + sub + k * 32) * 16;
#pragma unroll
    for (int c = 0; c < 16; ++c) g[c] += p[c];
  }
#pragma unroll
  for (int c = 0; c < 16; ++c) {
    float v = g[c];
    v += __shfl_xor(v, 1);  v += __shfl_xor(v, 2);
    v += __shfl_xor(v, 4);  v += __shfl_xor(v, 8);
    v += __shfl_xor(v, 16);
    g[c] = v * (1.f / 262144.f);
  }
  if (sub == 0) {
    float h[16];
#pragma unroll
    for (int j = 0; j < 16; ++j) {
      float s = 0.f;
#pragma unroll
      for (int c = 0; c < 16; ++c) s += g[c] * se_w1[j * 16 + c];
      h[j] = fmaxf(s, 0.f);
    }
#pragma unroll
    for (int i = 0; i < 5; ++i) {
      float s = 0.f;
#pragma unroll
      for (int j = 0; j < 16; ++j) s += h[j] * se_w2[i * 16 + j];
      float se = 1.f / (1.f + expf(-s));
      bd_eff[b * 10 + i]     = bd_w[i] * se;
      bd_eff[b * 10 + 5 + i] = bd_w[5 + i] * se;
    }
  }
}

// ---------------- Kernel 2b: repack fc_w -> wTab[s][oc][ci] bf16 ------------
__global__ void k_prep(const float* __restrict__ fc_w,
                       unsigned short* __restrict__ wTab) {
  int i = blockIdx.x * 256 + threadIdx.x;
  if (i < 4608) {
    int ci = i & 31, rest = i >> 5;
    int oc = rest & 15, s = rest >> 4;
    float v = fc_w[(oc * 32 + ci) * 9 + s];
    __hip_bfloat16 h = __float2bfloat16(v);
    wTab[i] = *reinterpret_cast<unsigned short*>(&h);
  }
}

// ---------------- Kernel 2c: pre-pass: fuse(bf16 NHWC) + bscale --------------
// Pure streaming: read y once, write 32B fuse + 4B bscale per px.
__global__ __launch_bounds__(256) void k_pre(
    const float* __restrict__ y, const float* __restrict__ fuse_w,
    const float* __restrict__ fuse_b, const float* __restrict__ bd_eff,
    const float* __restrict__ bd_b, unsigned short* __restrict__ fuseP,
    float* __restrict__ bscaleP) {
  __shared__ float fw[80], fb[16], bde[10], bdb[2];
  int tid = threadIdx.x;
  int b = blockIdx.x >> 7;                 // 128 blocks per batch
  if (tid < 80) fw[tid] = fuse_w[tid];
  else if (tid < 96)  fb[tid - 80]  = fuse_b[tid - 80];
  else if (tid < 106) bde[tid - 96] = bd_eff[b * 10 + tid - 96];
  else if (tid < 108) bdb[tid - 106] = bd_b[tid - 106];
  __syncthreads();

  const float* yb = y + (size_t)b * 5 * HW;
  int gof0 = (blockIdx.x & 127) * 2048;
#pragma unroll 1
  for (int i = 0; i < 2048; i += 256) {
    int gofs = gof0 + i + tid;
    float yv[5];
#pragma unroll
    for (int c = 0; c < 5; ++c) yv[c] = yb[c * HW + gofs];
    float fo[16];
#pragma unroll
    for (int o = 0; o < 16; ++o) {
      float a = fb[o];
#pragma unroll
      for (int c = 0; c < 5; ++c) a = fmaf(fw[o * 5 + c], yv[c], a);
      fo[o] = fmaxf(a, 0.f);
    }
    size_t po = ((size_t)b * HW + gofs) * 16;   // ushort index, 32B/px
    uint4v v0 = {bpack2(fo[0], fo[1]), bpack2(fo[2], fo[3]),
                 bpack2(fo[4], fo[5]), bpack2(fo[6], fo[7])};
    uint4v v1 = {bpack2(fo[8], fo[9]), bpack2(fo[10], fo[11]),
                 bpack2(fo[12], fo[13]), bpack2(fo[14], fo[15])};
    *reinterpret_cast<uint4v*>(fuseP + po) = v0;
    *reinterpret_cast<uint4v*>(fuseP + po + 8) = v1;
    float bl0 = bdb[0], bl1 = bdb[1];
#pragma unroll
    for (int c = 0; c < 5; ++c) {
      bl0 = fmaf(bde[c], yv[c], bl0);
      bl1 = fmaf(bde[5 + c], yv[c], bl1);
    }
    bscaleP[(size_t)b * HW + gofs] = 1.f / (1.f + __expf(bl0 - bl1));
  }
}

// ---------------- Kernel 3: fused main (MFMA implicit-GEMM conv) ------------
// 256 threads = 4 waves, tile 64x8, 3 blocks/CU. Wave wv owns rows 2wv,2wv+1.
// PRE=1: fuse/bscale from pre-pass. PRE=0: computed in staging (ws fallback).
template <int PRE>
__global__ __launch_bounds__(256) void k_main(
    const float* __restrict__ x, const float* __restrict__ y,
    const float* __restrict__ fuse_w, const float* __restrict__ fuse_b,
    const unsigned short* __restrict__ wTab,
    const unsigned short* __restrict__ fuseP,
    const float* __restrict__ bscaleP,
    const float* __restrict__ bd_eff, const float* __restrict__ bd_b,
    const float* __restrict__ fc_b,
    const float* __restrict__ fm_w, const float* __restrict__ fm_b,
    const float* __restrict__ cv_w, const float* __restrict__ cv_b,
    float* __restrict__ out) {
  __shared__ unsigned short tile[NHALO * ROWU];   // 52800 B
  __shared__ float s_fw[80], s_fb[16], s_bde[10], s_bdb[2], s_fm[32],
      s_fmb[2], s_cv[16], s_cvb[16], s_fcb[16];

  int tid = threadIdx.x;
  int bsel = blockIdx.z;
  int h0 = blockIdx.y * TH;
  int w0 = blockIdx.x * TW;

  if (tid < 80) s_fw[tid] = fuse_w[tid];
  else if (tid < 96)  s_fb[tid - 80]   = fuse_b[tid - 80];
  else if (tid < 106) s_bde[tid - 96]  = bd_eff[bsel * 10 + tid - 96];
  else if (tid < 108) s_bdb[tid - 106] = bd_b[tid - 106];
  else if (tid < 140) s_fm[tid - 108]  = fm_w[tid - 108];
  else if (tid < 142) s_fmb[tid - 140] = fm_b[tid - 140];
  else if (tid < 158) s_cv[tid - 142]  = cv_w[tid - 142];
  else if (tid < 174) s_cvb[tid - 158] = cv_b[tid - 158];
  else if (tid < 190) s_fcb[tid - 174] = fc_b[tid - 174];

  int lane = tid & 63, wv = tid >> 6;
  int l15 = lane & 15, q = lane >> 4;

  short8 afrag[9];
#pragma unroll
  for (int s = 0; s < 9; ++s)
    afrag[s] = *reinterpret_cast<const short8*>(wTab + (s * 16 + l15) * 32 + q * 8);

  __syncthreads();

  // ---- staging ----
  const float* yb = y + (size_t)bsel * 5 * HW;
  const float* xb = x + (size_t)bsel * 16 * HW;
#pragma unroll 1
  for (int p = tid; p < NHALO; p += 256) {
    int hr = p / HLW, wc = p - hr * HLW;
    int gh = h0 - 1 + hr, gw = w0 - 1 + wc;
    bool valid = (gh >= 0) & (gh < IW) & (gw >= 0) & (gw < IW);
    uint4v* dst = reinterpret_cast<uint4v*>(&tile[p * ROWU]);
    if (valid) {
      int gofs = gh * IW + gw;
      if (PRE) {
        size_t po = ((size_t)bsel * HW + gofs) * 16;
        uint4v f0 = *reinterpret_cast<const uint4v*>(fuseP + po);
        uint4v f1 = *reinterpret_cast<const uint4v*>(fuseP + po + 8);
        float bsc = bscaleP[(size_t)bsel * HW + gofs];
        float a0 = xb[gofs],          a1 = xb[HW + gofs];
        float a2 = xb[2 * HW + gofs], a3 = xb[3 * HW + gofs];
        float a4 = xb[4 * HW + gofs], a5 = xb[5 * HW + gofs];
        float a6 = xb[6 * HW + gofs], a7 = xb[7 * HW + gofs];
        float a8 = xb[8 * HW + gofs],  a9 = xb[9 * HW + gofs];
        float aA = xb[10 * HW + gofs], aB = xb[11 * HW + gofs];
        float aC = xb[12 * HW + gofs], aD = xb[13 * HW + gofs];
        float aE = xb[14 * HW + gofs], aF = xb[15 * HW + gofs];
        dst[0] = uint4v{bpack2(a0, a1), bpack2(a2, a3),
                        bpack2(a4, a5), bpack2(a6, a7)};
        dst[1] = uint4v{bpack2(a8, a9), bpack2(aA, aB),
                        bpack2(aC, aD), bpack2(aE, aF)};
        dst[2] = f0;
        dst[3] = f1;
        *reinterpret_cast<float*>(&tile[p * ROWU + 32]) = bsc;
      } else {
        {
          float a0 = xb[gofs],          a1 = xb[HW + gofs];
          float a2 = xb[2 * HW + gofs], a3 = xb[3 * HW + gofs];
          float a4 = xb[4 * HW + gofs], a5 = xb[5 * HW + gofs];
          float a6 = xb[6 * HW + gofs], a7 = xb[7 * HW + gofs];
          dst[0] = uint4v{bpack2(a0, a1), bpack2(a2, a3),
                          bpack2(a4, a5), bpack2(a6, a7)};
        }
        {
          float a0 = xb[8 * HW + gofs],  a1 = xb[9 * HW + gofs];
          float a2 = xb[10 * HW + gofs], a3 = xb[11 * HW + gofs];
          float a4 = xb[12 * HW + gofs], a5 = xb[13 * HW + gofs];
          float a6 = xb[14 * HW + gofs], a7 = xb[15 * HW + gofs];
          dst[1] = uint4v{bpack2(a0, a1), bpack2(a2, a3),
                          bpack2(a4, a5), bpack2(a6, a7)};
        }
        float yv[5];
#pragma unroll
        for (int c = 0; c < 5; ++c) yv[c] = yb[c * HW + gofs];
        float fo[8];
#pragma unroll
        for (int o = 0; o < 8; ++o) {
          float a = s_fb[o];
#pragma unroll
          for (int c = 0; c < 5; ++c) a = fmaf(s_fw[o * 5 + c], yv[c], a);
          fo[o] = fmaxf(a, 0.f);
        }
        dst[2] = uint4v{bpack2(fo[0], fo[1]), bpack2(fo[2], fo[3]),
                        bpack2(fo[4], fo[5]), bpack2(fo[6], fo[7])};
#pragma unroll
        for (int o = 0; o < 8; ++o) {
          float a = s_fb[8 + o];
#pragma unroll
          for (int c = 0; c < 5; ++c) a = fmaf(s_fw[(8 + o) * 5 + c], yv[c], a);
          fo[o] = fmaxf(a, 0.f);
        }
        dst[3] = uint4v{bpack2(fo[0], fo[1]), bpack2(fo[2], fo[3]),
                        bpack2(fo[4], fo[5]), bpack2(fo[6], fo[7])};
        float bl0 = s_bdb[0], bl1 = s_bdb[1];
#pragma unroll
        for (int c = 0; c < 5; ++c) {
          bl0 = fmaf(s_bde[c], yv[c], bl0);
          bl1 = fmaf(s_bde[5 + c], yv[c], bl1);
        }
        *reinterpret_cast<float*>(&tile[p * ROWU + 32]) =
            1.f / (1.f + __expf(bl0 - bl1));
      }
    } else {
      uint4v z = {0, 0, 0, 0};
      dst[0] = z; dst[1] = z; dst[2] = z; dst[3] = z;
      *reinterpret_cast<float*>(&tile[p * ROWU + 32]) = 0.f;
    }
  }
  __syncthreads();

  // ---- compute: 8 groups, tap-major MFMA (8-way ILP) ----
  const char* tb = reinterpret_cast<const char*>(tile);
  unsigned bofs[8];
  f32x4 acc[8];
#pragma unroll
  for (int g = 0; g < 8; ++g) {
    int row = 2 * wv + (g >> 2), c0 = (g & 3) * 16;
    bofs[g] = (unsigned)((row * HLW + c0 + l15) * (ROWU * 2) + q * 16);
    acc[g] = f32x4{0.f, 0.f, 0.f, 0.f};
  }
#pragma unroll
  for (int kh = 0; kh < 3; ++kh) {
#pragma unroll
    for (int kw = 0; kw < 3; ++kw) {
      short8 a = afrag[kh * 3 + kw];
#pragma unroll
      for (int g = 0; g < 8; ++g) {
        short8 bfr = *reinterpret_cast<const short8*>(
            tb + bofs[g] + (kh * HLW + kw) * (ROWU * 2));
        acc[g] = __builtin_amdgcn_mfma_f32_16x16x32_bf16(a, bfr, acc[g], 0, 0, 0);
      }
    }
  }

  // ---- batched epilogue ----
  float pm0[8], pm1[8];
#pragma unroll
  for (int g = 0; g < 8; ++g) {
    float p0 = 0.f, p1 = 0.f;
#pragma unroll
    for (int j = 0; j < 4; ++j) {
      int oc = q * 4 + j;
      float fv = fmaxf(acc[g][j] + s_fcb[oc], 0.f);
      p0 = fmaf(s_fm[oc], fv, p0);
      p1 = fmaf(s_fm[16 + oc], fv, p1);
    }
    pm0[g] = p0; pm1[g] = p1;
  }
#pragma unroll
  for (int g = 0; g < 8; ++g) pm0[g] += __shfl_xor(pm0[g], 16);
#pragma unroll
  for (int g = 0; g < 8; ++g) pm1[g] += __shfl_xor(pm1[g], 16);
#pragma unroll
  for (int g = 0; g < 8; ++g) pm0[g] += __shfl_xor(pm0[g], 32);
#pragma unroll
  for (int g = 0; g < 8; ++g) pm1[g] += __shfl_xor(pm1[g], 32);

  float sc[8];
#pragma unroll
  for (int g = 0; g < 8; ++g) {
    int row = 2 * wv + (g >> 2), c0 = (g & 3) * 16;
    float mscale =
        1.f / (1.f + __expf((pm0[g] + s_fmb[0]) - (pm1[g] + s_fmb[1])));
    float bsc = *reinterpret_cast<const float*>(
        tb + ((row + 1) * HLW + c0 + l15 + 1) * (ROWU * 2) + 64);
    sc[g] = fminf(fmaxf(mscale + bsc, 0.f), 1.f);
  }

  float* outb = out + (size_t)bsel * 16 * HW;
#pragma unroll
  for (int g = 0; g < 8; ++g) {
    int row = 2 * wv + (g >> 2), c0 = (g & 3) * 16;
    int gofs = (h0 + row) * IW + w0 + c0 + l15;
#pragma unroll
    for (int j = 0; j < 4; ++j) {
      int oc = q * 4 + j;
      outb[(size_t)oc * HW + gofs] = fmaf(s_cv[oc], sc[g], s_cvb[oc]);
    }
  }
}

extern "C" void kernel_launch(void* const* d_in, const int* in_sizes, int n_in,
                              void* d_out, int out_size, void* d_ws, size_t ws_size,
                              hipStream_t stream) {
  const float* x      = (const float*)d_in[0];
  const float* y      = (const float*)d_in[1];
  const float* fuse_w = (const float*)d_in[2];
  const float* fuse_b = (const float*)d_in[3];
  const float* se_w1  = (const float*)d_in[4];
  const float* se_w2  = (const float*)d_in[5];
  const float* bd_w   = (const float*)d_in[6];
  const float* bd_b   = (const float*)d_in[7];
  const float* fc_w   = (const float*)d_in[8];
  const float* fc_b   = (const float*)d_in[9];
  const float* fm_w   = (const float*)d_in[10];
  const float* fm_b   = (const float*)d_in[11];
  const float* cv_w   = (const float*)d_in[12];
  const float* cv_b   = (const float*)d_in[13];
  float* out = (float*)d_out;

  char* ws = (char*)d_ws;
  float* partial = (float*)ws;                          // 16384 f32
  float* bd_eff  = partial + 1024 * 16;                 // 80 f32
  unsigned short* wTab = (unsigned short*)(ws + (1024 * 16 + 80) * 4);  // 4608 u16
  size_t fuse_off = (((1024 * 16 + 80) * 4 + 4608 * 2) + 255) & ~(size_t)255;
  unsigned short* fuseP = (unsigned short*)(ws + fuse_off);     // 2M px * 32B
  float* bscaleP = (float*)(ws + fuse_off + (size_t)2097152 * 32);  // 2M f32
  size_t need = fuse_off + (size_t)2097152 * 32 + (size_t)2097152 * 4;
  bool pre = ws_size >= need;

  k_gap<<<1024, 256, 0, stream>>>(y, fuse_w, fuse_b, partial);
  k_se<<<1, 256, 0, stream>>>(partial, se_w1, se_w2, bd_w, bd_eff);
  k_prep<<<18, 256, 0, stream>>>(fc_w, wTab);
  if (pre) {
    k_pre<<<1024, 256, 0, stream>>>(y, fuse_w, fuse_b, bd_eff, bd_b, fuseP,
                                    bscaleP);
    k_main<1><<<dim3(8, 64, 8), 256, 0, stream>>>(
        x, y, fuse_w, fuse_b, wTab, fuseP, bscaleP, bd_eff, bd_b, fc_b, fm_w,
        fm_b, cv_w, cv_b, out);
  } else {
    k_main<0><<<dim3(8, 64, 8), 256, 0, stream>>>(
        x, y, fuse_w, fuse_b, wTab, fuseP, bscaleP, bd_eff, bd_b, fc_b, fm_w,
        fm_b, cv_w, cv_b, out);
  }
}